// Round 15
// baseline (84.467 us; speedup 1.0000x reference)
//
#include <hip/hip_runtime.h>
#include <math.h>
#include <stdint.h>

// IntGELU — interval-hedged pipeline, v15: math bit-identical to v13/v14;
// structure: ONE WAVE PER ROW, TPB=256 (4 independent rows per block).
//  - no LDS, no __syncthreads -> no vmcnt-draining barrier per row
//    (v13's 40% VALU-idle was load-wait + barrier drain per block-row).
//  - two passes over the row: pass1 stream -> wave max (6 shfl_xor);
//    pass2 RE-LOADS the row (L2/L3-resident) and computes/stores.
//    Nothing kept in registers -> ~30 VGPR -> 8 waves/SIMD TLP.
//  - exact floor((2^31-1)/s): q0=(u32)(CBIAS*rcp(s)), CBIAS=2^31-768 biases
//    into {F-1,F}; one upward remainder fixup (v13-proven).
//  - fast path branchless: out=(x*2^-8)*(sigLo+sigHi); per-row wave-vote
//    dmax>=3 fallback (dsig<=2 => W < threshold for |x|<=12).

constexpr int H   = 3072;
constexpr int TPB = 256;
constexpr int WPB = TPB / 64;    // 4 rows (waves) per block
constexpr int V4  = H / 4;       // 768 float4 per row
constexpr int LPW = V4 / 64;     // 12 float4 per lane

constexpr uint32_t MU32  = 2147483647u;
constexpr float    CBIAS = 2147482880.0f;   // 2^31 - 768
constexpr float    WT2   = 0.19365f * 0.5f;

__device__ __forceinline__ uint32_t fix_up(uint32_t q, uint32_t s) {
    uint32_t rem = MU32 - q * s;            // q*s <= M -> no wrap
    return q + ((rem >= s) ? 1u : 0u);
}

__device__ __forceinline__ float rcpf(float x) {
#if __has_builtin(__builtin_amdgcn_rcpf)
    return __builtin_amdgcn_rcpf(x);
#else
    return 1.0f / x;
#endif
}

__device__ __forceinline__ float eiarg_f(float xv, float xmf, float rsff,
                                         float mx0f, float n23x0f, float rx0f)
{
    float xi = (xv - xmf) * rsff;           // <= ~0
    float t  = (xi + floorf(xi * 0.5f)) - floorf(xi * 0.0625f);
    t = fmaxf(t, n23x0f);
    int   qi = (int)(t * rx0f);             // q in [0,23]
    float qd = (float)qi;
    float r  = fmaf(mx0f, qd, t);           // t - x0*q
    float e  = fmaf(r, 0.5f, mx0f);         // e in (15, 30]
    return ldexpf(e, 23 - qi);              // v_ldexp_f32
}

__device__ __forceinline__ float elem_fast(float xv, float xmf, float rsff,
                                           float mx0f, float n23x0f, float rx0f,
                                           uint32_t emax_u, uint32_t& dmax)
{
    float eiarg = eiarg_f(xv, xmf, rsff, mx0f, n23x0f, rx0f);
    float del = fmaf(4.4e-6f, eiarg, 8.0f);
    uint32_t uL = (uint32_t)(eiarg - del);
    uint32_t uH = (uint32_t)(eiarg + del);
    uint32_t sL = uL + emax_u;
    uint32_t sH = uH + emax_u;
    uint32_t FH = fix_up((uint32_t)(CBIAS * rcpf((float)sL)), sL);
    uint32_t FL = fix_up((uint32_t)(CBIAS * rcpf((float)sH)), sH);
    uint32_t sigLo = (uL * FL) >> 24;
    uint32_t sigHi = (uH * FH) >> 24;
    dmax = max(dmax, sigHi - sigLo);
    return (xv * 0.00390625f) * (float)(sigLo + sigHi);
}

// rare path (wave saw dsig >= 3): exact v10-v14 semantics
__device__ __noinline__ float elem_full(float xv, float xmf, float rsff,
                                        float mx0f, float n23x0f, float rx0f,
                                        uint32_t emax_u)
{
    float eiarg = eiarg_f(xv, xmf, rsff, mx0f, n23x0f, rx0f);
    float del = fmaf(4.4e-6f, eiarg, 8.0f);
    uint32_t uL = (uint32_t)(eiarg - del);
    uint32_t uH = (uint32_t)(eiarg + del);
    uint32_t sL = uL + emax_u;
    uint32_t sH = uH + emax_u;
    uint32_t FH = fix_up((uint32_t)(CBIAS * rcpf((float)sL)), sL);
    uint32_t FL = fix_up((uint32_t)(CBIAS * rcpf((float)sH)), sH);
    uint32_t sigLo = (uL * FL) >> 24;
    uint32_t sigHi = (uH * FH) >> 24;
    float m05 = xv * 0.00390625f;
    float W = fabsf(m05) * (float)(sigHi - sigLo);
    if (W <= WT2) return m05 * (float)(sigLo + sigHi);
    uint32_t ei_u = (uint32_t)eiarg;
    uint32_t sb   = ei_u + emax_u;
    uint32_t fb   = fix_up((uint32_t)(CBIAS * rcpf((float)sb)), sb);
    uint32_t sigb = (ei_u * fb) >> 24;
    return (xv * 0.0078125f) * (float)sigb;
}

__global__ __launch_bounds__(TPB) void ig_ivhedge_v15(
    const float* __restrict__ xin, const float* __restrict__ sfin,
    float* __restrict__ yout, int nrow)
{
    const int lane = threadIdx.x & 63;
    const int row  = blockIdx.x * WPB + (threadIdx.x >> 6);

    const float sff    = sfin[0];
    const float rsff   = 1.0f / sff;
    const double x0d   = floor(-1.0 / ((double)sff * 1.702));
    const float mx0f   = (float)(-x0d);              // 30, exact
    const float n23x0f = (float)(23.0 * x0d);        // -690, exact
    const float rx0f   = (float)(1.0 / x0d);
    const float osf    = sff * 0.0078125f;

    if (row < nrow) {
        const float4* xr = reinterpret_cast<const float4*>(xin) + (size_t)row * V4;
        float4*       yr = reinterpret_cast<float4*>(yout)      + (size_t)row * V4;

        // Pass 1: stream row -> wave max (nothing kept).
        float mx = -3.402823466e38f;
#pragma unroll
        for (int i = 0; i < LPW; ++i) {
            float4 w = xr[lane + i * 64];
            mx = fmaxf(fmaxf(mx, fmaxf(w.x, w.y)), fmaxf(w.z, w.w));
        }
#pragma unroll
        for (int d = 32; d >= 1; d >>= 1)
            mx = fmaxf(mx, __shfl_xor(mx, d, 64));

        const uint32_t emax_u =
            (uint32_t)eiarg_f(0.0f, mx, rsff, mx0f, n23x0f, rx0f);

        // Pass 2: re-load row (L2/L3-resident), compute, store.
        uint32_t dmax = 0u;
#pragma unroll
        for (int i = 0; i < LPW; ++i) {
            float4 w = xr[lane + i * 64];
            float4 o;
            o.x = elem_fast(w.x, mx, rsff, mx0f, n23x0f, rx0f, emax_u, dmax);
            o.y = elem_fast(w.y, mx, rsff, mx0f, n23x0f, rx0f, emax_u, dmax);
            o.z = elem_fast(w.z, mx, rsff, mx0f, n23x0f, rx0f, emax_u, dmax);
            o.w = elem_fast(w.w, mx, rsff, mx0f, n23x0f, rx0f, emax_u, dmax);
            yr[lane + i * 64] = o;
        }

        // dsig<=2 => W <= 2|x|/256 < WT2 for |x|<=12: no fallback possible.
        if (__any(dmax >= 3u)) {
#pragma unroll
            for (int i = 0; i < LPW; ++i) {
                float4 w = xr[lane + i * 64];
                float4 o;
                o.x = elem_full(w.x, mx, rsff, mx0f, n23x0f, rx0f, emax_u);
                o.y = elem_full(w.y, mx, rsff, mx0f, n23x0f, rx0f, emax_u);
                o.z = elem_full(w.z, mx, rsff, mx0f, n23x0f, rx0f, emax_u);
                o.w = elem_full(w.w, mx, rsff, mx0f, n23x0f, rx0f, emax_u);
                yr[lane + i * 64] = o;
            }
        }
    }

    if (blockIdx.x == 0 && threadIdx.x == 0)
        yout[(size_t)nrow * H] = osf;
}

extern "C" void kernel_launch(void* const* d_in, const int* in_sizes, int n_in,
                              void* d_out, int out_size, void* d_ws, size_t ws_size,
                              hipStream_t stream) {
    const float* x  = (const float*)d_in[0];
    const float* sf = (const float*)d_in[1];
    float* out = (float*)d_out;
    const int total = in_sizes[0];       // 64*196*3072
    const int nrow  = total / H;         // 12544
    const int nblk  = (nrow + WPB - 1) / WPB;   // 3136
    ig_ivhedge_v15<<<nblk, TPB, 0, stream>>>(x, sf, out, nrow);
}